// Round 5
// baseline (938.806 us; speedup 1.0000x reference)
//
#include <hip/hip_runtime.h>
#include <stdint.h>

// ---------------------------------------------------------------------------
// BasicTransformerBlock on MI355X (gfx950).
// B=8, N=2048, D=512, S=256, CD=768, H=8, DH=64, INNER=512, FF=2048.
// Inputs f32, OUTPUT F32 (reference returns f32). bf16 MFMA internally.
// ---------------------------------------------------------------------------

typedef __bf16 bf16x8 __attribute__((ext_vector_type(8)));
typedef float f32x4 __attribute__((ext_vector_type(4)));

__device__ __forceinline__ unsigned short f2b(float f) {
  union { float f; unsigned u; } v; v.f = f;
  return (unsigned short)((v.u + 0x7FFFu + ((v.u >> 16) & 1u)) >> 16);
}
__device__ __forceinline__ float b2f(unsigned short s) {
  union { unsigned u; float f; } v; v.u = ((unsigned)s) << 16; return v.f;
}
__device__ __forceinline__ f32x4 mfma16(bf16x8 a, bf16x8 b, f32x4 c) {
  return __builtin_amdgcn_mfma_f32_16x16x32_bf16(a, b, c, 0, 0, 0);
}

// ---------------- weight transpose + cast: in[R,C] f32 -> out[C,R] bf16 -----
__global__ __launch_bounds__(256) void wtrans(const float* __restrict__ in,
                                              unsigned short* __restrict__ out,
                                              int R, int C) {
  __shared__ unsigned short t[32][33];
  int tx = threadIdx.x & 31, ty = threadIdx.x >> 5;  // 32 x 8
  int c0 = blockIdx.x * 32, r0 = blockIdx.y * 32;
#pragma unroll
  for (int i = 0; i < 32; i += 8)
    t[ty + i][tx] = f2b(in[(size_t)(r0 + ty + i) * C + c0 + tx]);
  __syncthreads();
#pragma unroll
  for (int i = 0; i < 32; i += 8)
    out[(size_t)(c0 + ty + i) * R + r0 + tx] = t[tx][ty + i];
}

// ---------------- plain cast f32 -> bf16 (vector x4) ------------------------
__global__ __launch_bounds__(256) void castbf(const float* __restrict__ in,
                                              unsigned short* __restrict__ out,
                                              int n4) {
  int i = blockIdx.x * 256 + threadIdx.x;
  if (i >= n4) return;
  float4 v = ((const float4*)in)[i];
  unsigned long long p = (unsigned long long)f2b(v.x) |
                         ((unsigned long long)f2b(v.y) << 16) |
                         ((unsigned long long)f2b(v.z) << 32) |
                         ((unsigned long long)f2b(v.w) << 48);
  ((unsigned long long*)out)[i] = p;
}

// ---------------- LayerNorm rows of 512: f32 in -> bf16 out -----------------
__global__ __launch_bounds__(256) void ln_rows(const float* __restrict__ x,
                                               const float* __restrict__ g,
                                               const float* __restrict__ bb,
                                               unsigned short* __restrict__ out) {
  int row = blockIdx.x * 4 + (threadIdx.x >> 6);
  int lane = threadIdx.x & 63;
  const float* xr = x + (size_t)row * 512 + lane * 8;
  float4 a = *(const float4*)xr;
  float4 c = *(const float4*)(xr + 4);
  float av[8] = {a.x, a.y, a.z, a.w, c.x, c.y, c.z, c.w};
  float s = 0.f, q = 0.f;
#pragma unroll
  for (int j = 0; j < 8; j++) { s += av[j]; q += av[j] * av[j]; }
#pragma unroll
  for (int d = 1; d < 64; d <<= 1) { s += __shfl_xor(s, d); q += __shfl_xor(q, d); }
  float mean = s * (1.f / 512.f);
  float var = q * (1.f / 512.f) - mean * mean;
  float rs = rsqrtf(var + 1e-5f);
  const float* gp = g + lane * 8;
  const float* bp = bb + lane * 8;
  unsigned rr[4];
#pragma unroll
  for (int j = 0; j < 4; j++) {
    float y0 = (av[2 * j] - mean) * rs * gp[2 * j] + bp[2 * j];
    float y1 = (av[2 * j + 1] - mean) * rs * gp[2 * j + 1] + bp[2 * j + 1];
    rr[j] = (unsigned)f2b(y0) | ((unsigned)f2b(y1) << 16);
  }
  *(uint4*)(out + (size_t)row * 512 + lane * 8) = make_uint4(rr[0], rr[1], rr[2], rr[3]);
}

// ---------------- GEMM: C[M,N] = A[M,K] @ Bt[N,K]^T, bf16 in, f32 acc -------
// EPI 0: bf16 out;  1: bf16 out + bias;  2: f32 out = acc + bias + res
template <int EPI>
__global__ __launch_bounds__(256) void gemm128(const unsigned short* __restrict__ A,
                                               const unsigned short* __restrict__ Bt,
                                               void* __restrict__ Cp,
                                               const float* __restrict__ bias,
                                               const float* __restrict__ res,
                                               int M, int N, int K) {
  __shared__ unsigned short As[128 * 32];
  __shared__ unsigned short Bs[128 * 32];
  int tid = threadIdx.x;
  int wave = tid >> 6, lane = tid & 63;
  int row0 = blockIdx.x * 128, col0 = blockIdx.y * 128;
  int wr = wave >> 1, wc = wave & 1;
  f32x4 acc[4][4] = {};
  int sr = tid >> 1, sk = (tid & 1) << 4;
  const unsigned short* gA = A + (size_t)(row0 + sr) * K + sk;
  const unsigned short* gB = Bt + (size_t)(col0 + sr) * K + sk;
  int l15 = lane & 15, l4 = (lane >> 4) << 3;
  int rA = (wr * 64 + l15) * 32 + l4;
  int rB = (wc * 64 + l15) * 32 + l4;
  for (int kt = 0; kt < K; kt += 32) {
    *(uint4*)&As[sr * 32 + sk] = *(const uint4*)(gA + kt);
    *(uint4*)&As[sr * 32 + sk + 8] = *(const uint4*)(gA + kt + 8);
    *(uint4*)&Bs[sr * 32 + sk] = *(const uint4*)(gB + kt);
    *(uint4*)&Bs[sr * 32 + sk + 8] = *(const uint4*)(gB + kt + 8);
    __syncthreads();
    bf16x8 af[4], bq[4];
#pragma unroll
    for (int m = 0; m < 4; m++) af[m] = *(const bf16x8*)&As[rA + m * 16 * 32];
#pragma unroll
    for (int n = 0; n < 4; n++) bq[n] = *(const bf16x8*)&Bs[rB + n * 16 * 32];
#pragma unroll
    for (int m = 0; m < 4; m++)
#pragma unroll
      for (int n = 0; n < 4; n++)
        acc[m][n] = mfma16(af[m], bq[n], acc[m][n]);
    __syncthreads();
  }
  int lr = (lane >> 4) * 4;
#pragma unroll
  for (int m = 0; m < 4; m++)
#pragma unroll
    for (int n = 0; n < 4; n++)
#pragma unroll
      for (int r = 0; r < 4; r++) {
        int grow = row0 + wr * 64 + m * 16 + lr + r;
        int gcol = col0 + wc * 64 + n * 16 + l15;
        size_t gi = (size_t)grow * N + gcol;
        float v = acc[m][n][r];
        if (EPI == 0) {
          ((unsigned short*)Cp)[gi] = f2b(v);
        } else if (EPI == 1) {
          ((unsigned short*)Cp)[gi] = f2b(v + bias[gcol]);
        } else {
          ((float*)Cp)[gi] = v + bias[gcol] + res[gi];
        }
      }
}

// ---------------- flash attention -------------------------------------------
// grid (nq/64, H=8, B=8); 4 waves x 16 q-rows; KV tiles of 32 keys.
__global__ __launch_bounds__(256) void attn(const unsigned short* __restrict__ Q,
                                            const unsigned short* __restrict__ Kg,
                                            const unsigned short* __restrict__ Vg,
                                            unsigned short* __restrict__ O,
                                            const int* __restrict__ lengths,
                                            int nq, int nkv, int maskkv) {
  int qblk = blockIdx.x, h = blockIdx.y, b = blockIdx.z;
  int tid = threadIdx.x, wave = tid >> 6, lane = tid & 63;
  int len = lengths[b];
  int qbase = qblk * 64;
  if (qbase >= len) return;  // padded q-rows: output masked to 0 at the end
  int kvlen = maskkv ? len : nkv;
  int nt = (kvlen + 31) >> 5;

  __shared__ unsigned short Ks[32][72];   // [key][dh], +8 pad
  __shared__ unsigned short Vf[2048];     // [kgrp 4][dh 64][kj 8] frag-ready
  __shared__ unsigned short Ps[4][16][40];// per-wave P tile [q 16][key 32]+pad

  int l15 = lane & 15, lh = lane >> 4, l4 = lh * 8;
  const unsigned short* qp =
      Q + (size_t)(b * nq + qbase + wave * 16 + l15) * 512 + h * 64 + l4;
  bf16x8 aq0 = *(const bf16x8*)qp;
  bf16x8 aq1 = *(const bf16x8*)(qp + 32);
  const unsigned short* kgp = Kg + (size_t)b * nkv * 512 + h * 64;
  const unsigned short* vgp = Vg + (size_t)b * nkv * 512 + h * 64;

  f32x4 oacc[4] = {};
  float m_r[4], l_r[4];
#pragma unroll
  for (int r = 0; r < 4; r++) { m_r[r] = -3e38f; l_r[r] = 0.f; }

  int skey = tid >> 3, sd0 = (tid & 7) * 8;  // K staging
  int vdh = tid & 63, vkg = tid >> 6;        // V staging

  for (int t = 0; t < nt; t++) {
    int kv0 = t * 32;
    *(uint4*)&Ks[skey][sd0] =
        *(const uint4*)(kgp + (size_t)(kv0 + skey) * 512 + sd0);
    {
      unsigned short tmp[8];
#pragma unroll
      for (int kj = 0; kj < 8; kj++)
        tmp[kj] = vgp[(size_t)(kv0 + vkg * 8 + kj) * 512 + vdh];
      unsigned w0 = (unsigned)tmp[0] | ((unsigned)tmp[1] << 16);
      unsigned w1 = (unsigned)tmp[2] | ((unsigned)tmp[3] << 16);
      unsigned w2 = (unsigned)tmp[4] | ((unsigned)tmp[5] << 16);
      unsigned w3 = (unsigned)tmp[6] | ((unsigned)tmp[7] << 16);
      *(uint4*)&Vf[(vkg * 64 + vdh) * 8] = make_uint4(w0, w1, w2, w3);
    }
    __syncthreads();

    // S = Q K^T * scale (two 16x16 col-fragments)
    f32x4 sf[2];
#pragma unroll
    for (int c = 0; c < 2; c++) {
      bf16x8 bk0 = *(const bf16x8*)&Ks[c * 16 + l15][l4];
      bf16x8 bk1 = *(const bf16x8*)&Ks[c * 16 + l15][32 + l4];
      f32x4 z = {};
      z = mfma16(aq0, bk0, z);
      z = mfma16(aq1, bk1, z);
      sf[c] = z;
    }
#pragma unroll
    for (int c = 0; c < 2; c++) {
      bool kval = (kv0 + c * 16 + l15) < kvlen;
#pragma unroll
      for (int r = 0; r < 4; r++)
        sf[c][r] = kval ? sf[c][r] * 0.125f : -1e30f;
    }
    // online softmax (rows live across 16 lanes: xor 1,2,4,8)
    float mt[4], ps[4];
#pragma unroll
    for (int r = 0; r < 4; r++) mt[r] = fmaxf(sf[0][r], sf[1][r]);
#pragma unroll
    for (int d = 1; d < 16; d <<= 1)
#pragma unroll
      for (int r = 0; r < 4; r++) mt[r] = fmaxf(mt[r], __shfl_xor(mt[r], d));
    float sc[4];
#pragma unroll
    for (int r = 0; r < 4; r++) {
      float mn = fmaxf(m_r[r], mt[r]);
      sc[r] = __expf(m_r[r] - mn);
      m_r[r] = mn;
      ps[r] = 0.f;
    }
#pragma unroll
    for (int c = 0; c < 2; c++)
#pragma unroll
      for (int r = 0; r < 4; r++) {
        float pe = __expf(sf[c][r] - m_r[r]);
        ps[r] += pe;
        Ps[wave][lh * 4 + r][c * 16 + l15] = f2b(pe);
      }
#pragma unroll
    for (int d = 1; d < 16; d <<= 1)
#pragma unroll
      for (int r = 0; r < 4; r++) ps[r] += __shfl_xor(ps[r], d);
#pragma unroll
    for (int r = 0; r < 4; r++) l_r[r] = l_r[r] * sc[r] + ps[r];
#pragma unroll
    for (int nf = 0; nf < 4; nf++)
#pragma unroll
      for (int r = 0; r < 4; r++) oacc[nf][r] *= sc[r];
    // O += P V
    bf16x8 pf = *(const bf16x8*)&Ps[wave][l15][l4];
#pragma unroll
    for (int nf = 0; nf < 4; nf++) {
      bf16x8 vf = *(const bf16x8*)&Vf[(lh * 64 + nf * 16 + l15) * 8];
      oacc[nf] = mfma16(pf, vf, oacc[nf]);
    }
    __syncthreads();
  }
#pragma unroll
  for (int nf = 0; nf < 4; nf++)
#pragma unroll
    for (int r = 0; r < 4; r++) {
      float ov = oacc[nf][r] / l_r[r];
      int qrow = qbase + wave * 16 + lh * 4 + r;
      O[(size_t)(b * nq + qrow) * 512 + h * 64 + nf * 16 + l15] = f2b(ov);
    }
}

// ---------------- GEGLU: p[rows,4096] -> out[rows,2048] ---------------------
__global__ __launch_bounds__(256) void geglu(const unsigned short* __restrict__ p,
                                             unsigned short* __restrict__ out) {
  int idx = blockIdx.x * 256 + threadIdx.x;
  int row = idx >> 8, c = (idx & 255) << 3;
  const unsigned short* pr = p + (size_t)row * 4096 + c;
  uint4 av = *(const uint4*)pr;
  uint4 gv = *(const uint4*)(pr + 2048);
  const unsigned short* ap = (const unsigned short*)&av;
  const unsigned short* gp = (const unsigned short*)&gv;
  unsigned rr[4];
#pragma unroll
  for (int j = 0; j < 4; j++) {
    float a0 = b2f(ap[2 * j]), a1 = b2f(ap[2 * j + 1]);
    float x0 = b2f(gp[2 * j]), x1 = b2f(gp[2 * j + 1]);
    float y0 = a0 * 0.5f * x0 * (1.f + erff(x0 * 0.70710678118f));
    float y1 = a1 * 0.5f * x1 * (1.f + erff(x1 * 0.70710678118f));
    rr[j] = (unsigned)f2b(y0) | ((unsigned)f2b(y1) << 16);
  }
  *(uint4*)(out + (size_t)row * 2048 + c) = make_uint4(rr[0], rr[1], rr[2], rr[3]);
}

// ---------------- final mask: f32 XBUF -> f32 OUT (reference dtype!) --------
__global__ __launch_bounds__(256) void maskout_f32(const float* __restrict__ xb,
                                                   const int* __restrict__ lengths,
                                                   float* __restrict__ out) {
  int idx = blockIdx.x * 256 + threadIdx.x;
  int row = idx >> 6, c = (idx & 63) << 3;
  int b = row >> 11, n = row & 2047;
  bool val = n < lengths[b];
  float4 v0 = make_float4(0.f, 0.f, 0.f, 0.f), v1 = v0;
  if (val) {
    const float* xr = xb + (size_t)row * 512 + c;
    v0 = *(const float4*)xr;
    v1 = *(const float4*)(xr + 4);
  }
  float* orp = out + (size_t)row * 512 + c;
  *(float4*)orp = v0;
  *(float4*)(orp + 4) = v1;
}

// ---------------------------------------------------------------------------
extern "C" void kernel_launch(void* const* d_in, const int* in_sizes, int n_in,
                              void* d_out, int out_size, void* d_ws, size_t ws_size,
                              hipStream_t stream) {
  const float* x = (const float*)d_in[0];
  const float* ctx = (const float*)d_in[1];
  const int* lengths = (const int*)d_in[2];
  const float* wq1 = (const float*)d_in[3];
  const float* wk1 = (const float*)d_in[4];
  const float* wv1 = (const float*)d_in[5];
  const float* wo1 = (const float*)d_in[6];
  const float* bo1 = (const float*)d_in[7];
  const float* wq2 = (const float*)d_in[8];
  const float* wk2 = (const float*)d_in[9];
  const float* wv2 = (const float*)d_in[10];
  const float* wo2 = (const float*)d_in[11];
  const float* bo2 = (const float*)d_in[12];
  const float* wffin = (const float*)d_in[13];
  const float* bffin = (const float*)d_in[14];
  const float* wffout = (const float*)d_in[15];
  const float* bffout = (const float*)d_in[16];
  const float* g1 = (const float*)d_in[17];
  const float* b1 = (const float*)d_in[18];
  const float* g2 = (const float*)d_in[19];
  const float* b2 = (const float*)d_in[20];
  const float* g3 = (const float*)d_in[21];
  const float* b3 = (const float*)d_in[22];

  char* ws = (char*)d_ws;
  size_t o = 0;
  auto alloc = [&](size_t bytes) {
    size_t r = o;
    o += (bytes + 255) & ~(size_t)255;
    return r;
  };
  unsigned short* WQ1T = (unsigned short*)(ws + alloc(512 * 512 * 2));
  unsigned short* WK1T = (unsigned short*)(ws + alloc(512 * 512 * 2));
  unsigned short* WV1T = (unsigned short*)(ws + alloc(512 * 512 * 2));
  unsigned short* WO1T = (unsigned short*)(ws + alloc(512 * 512 * 2));
  unsigned short* WQ2T = (unsigned short*)(ws + alloc(512 * 512 * 2));
  unsigned short* WK2T = (unsigned short*)(ws + alloc(512 * 768 * 2));
  unsigned short* WV2T = (unsigned short*)(ws + alloc(512 * 768 * 2));
  unsigned short* WO2T = (unsigned short*)(ws + alloc(512 * 512 * 2));
  unsigned short* WFFINT = (unsigned short*)(ws + alloc(4096 * 512 * 2));
  unsigned short* WFFOUTT = (unsigned short*)(ws + alloc(512 * 2048 * 2));
  float* XBUF = (float*)(ws + alloc((size_t)16384 * 512 * 4));
  unsigned short* HB = (unsigned short*)(ws + alloc((size_t)16384 * 512 * 2));
  unsigned short* QB = (unsigned short*)(ws + alloc((size_t)16384 * 512 * 2));
  unsigned short* KB = (unsigned short*)(ws + alloc((size_t)16384 * 512 * 2));
  unsigned short* VB = (unsigned short*)(ws + alloc((size_t)16384 * 512 * 2));
  unsigned short* AO = (unsigned short*)(ws + alloc((size_t)16384 * 512 * 2));
  // phase-local aliases
  unsigned short* CTXB = KB;                                   // 3 MB (attn2 only)
  unsigned short* K2B = KB + (size_t)4 * 1024 * 1024 / 2;      // 2 MB at +4MB
  unsigned short* V2B = KB + (size_t)8 * 1024 * 1024 / 2;      // 2 MB at +8MB
  unsigned short* PCH = QB;   // spans QB..KB (32 MB contiguous) during FF
  unsigned short* GCH = VB;   // 16 MB during FF

  // weight prep
  wtrans<<<dim3(16, 16), 256, 0, stream>>>(wq1, WQ1T, 512, 512);
  wtrans<<<dim3(16, 16), 256, 0, stream>>>(wk1, WK1T, 512, 512);
  wtrans<<<dim3(16, 16), 256, 0, stream>>>(wv1, WV1T, 512, 512);
  wtrans<<<dim3(16, 16), 256, 0, stream>>>(wo1, WO1T, 512, 512);
  wtrans<<<dim3(16, 16), 256, 0, stream>>>(wq2, WQ2T, 512, 512);
  wtrans<<<dim3(16, 24), 256, 0, stream>>>(wk2, WK2T, 768, 512);
  wtrans<<<dim3(16, 24), 256, 0, stream>>>(wv2, WV2T, 768, 512);
  wtrans<<<dim3(16, 16), 256, 0, stream>>>(wo2, WO2T, 512, 512);
  wtrans<<<dim3(128, 16), 256, 0, stream>>>(wffin, WFFINT, 512, 4096);
  wtrans<<<dim3(16, 64), 256, 0, stream>>>(wffout, WFFOUTT, 2048, 512);

  // --- attn1 (self, key-masked) ---
  ln_rows<<<4096, 256, 0, stream>>>(x, g1, b1, HB);
  gemm128<0><<<dim3(128, 4), 256, 0, stream>>>(HB, WQ1T, QB, nullptr, nullptr, 16384, 512, 512);
  gemm128<0><<<dim3(128, 4), 256, 0, stream>>>(HB, WK1T, KB, nullptr, nullptr, 16384, 512, 512);
  gemm128<0><<<dim3(128, 4), 256, 0, stream>>>(HB, WV1T, VB, nullptr, nullptr, 16384, 512, 512);
  attn<<<dim3(32, 8, 8), 256, 0, stream>>>(QB, KB, VB, AO, lengths, 2048, 2048, 1);
  gemm128<2><<<dim3(128, 4), 256, 0, stream>>>(AO, WO1T, XBUF, bo1, x, 16384, 512, 512);

  // --- attn2 (cross, dense context) ---
  // castbf runs HERE: CTXB aliases KB, which attn1's K-projection used.
  ln_rows<<<4096, 256, 0, stream>>>(XBUF, g2, b2, HB);
  castbf<<<1536, 256, 0, stream>>>(ctx, CTXB, 2048 * 768 / 4);
  gemm128<0><<<dim3(128, 4), 256, 0, stream>>>(HB, WQ2T, QB, nullptr, nullptr, 16384, 512, 512);
  gemm128<0><<<dim3(16, 4), 256, 0, stream>>>(CTXB, WK2T, K2B, nullptr, nullptr, 2048, 512, 768);
  gemm128<0><<<dim3(16, 4), 256, 0, stream>>>(CTXB, WV2T, V2B, nullptr, nullptr, 2048, 512, 768);
  attn<<<dim3(32, 8, 8), 256, 0, stream>>>(QB, K2B, V2B, AO, lengths, 2048, 256, 0);
  gemm128<2><<<dim3(128, 4), 256, 0, stream>>>(AO, WO2T, XBUF, bo2, XBUF, 16384, 512, 512);

  // --- GEGLU FF, 4 row-chunks of 4096 ---
  ln_rows<<<4096, 256, 0, stream>>>(XBUF, g3, b3, HB);
  for (int ch = 0; ch < 4; ch++) {
    const unsigned short* hc = HB + (size_t)ch * 4096 * 512;
    float* xc = XBUF + (size_t)ch * 4096 * 512;
    gemm128<1><<<dim3(32, 32), 256, 0, stream>>>(hc, WFFINT, PCH, bffin, nullptr, 4096, 4096, 512);
    geglu<<<4096, 256, 0, stream>>>(PCH, GCH);
    gemm128<2><<<dim3(32, 4), 256, 0, stream>>>(GCH, WFFOUTT, xc, bffout, xc, 4096, 512, 2048);
  }

  maskout_f32<<<4096, 256, 0, stream>>>(XBUF, lengths, (float*)d_out);
}

// Round 8
// 924.139 us; speedup vs baseline: 1.0159x; 1.0159x over previous
//
#include <hip/hip_runtime.h>
#include <stdint.h>

// ---------------------------------------------------------------------------
// BasicTransformerBlock on MI355X (gfx950).
// B=8, N=2048, D=512, S=256, CD=768, H=8, DH=64, INNER=512, FF=2048.
// Inputs f32, OUTPUT F32. bf16 MFMA internally.
// R8: gemm128 staged via global_load_lds(16B); FF-out epilogue fuses
//     bias+residual+length-mask -> d_out (maskout pass deleted).
// ---------------------------------------------------------------------------

typedef __bf16 bf16x8 __attribute__((ext_vector_type(8)));
typedef float f32x4 __attribute__((ext_vector_type(4)));

__device__ __forceinline__ unsigned short f2b(float f) {
  union { float f; unsigned u; } v; v.f = f;
  return (unsigned short)((v.u + 0x7FFFu + ((v.u >> 16) & 1u)) >> 16);
}
__device__ __forceinline__ float b2f(unsigned short s) {
  union { unsigned u; float f; } v; v.u = ((unsigned)s) << 16; return v.f;
}
__device__ __forceinline__ f32x4 mfma16(bf16x8 a, bf16x8 b, f32x4 c) {
  return __builtin_amdgcn_mfma_f32_16x16x32_bf16(a, b, c, 0, 0, 0);
}
__device__ __forceinline__ void gload16(const void* g, void* l) {
  __builtin_amdgcn_global_load_lds((const __attribute__((address_space(1))) void*)g,
                                   (__attribute__((address_space(3))) void*)l,
                                   16, 0, 0);
}

// ---------------- weight transpose + cast: in[R,C] f32 -> out[C,R] bf16 -----
__global__ __launch_bounds__(256) void wtrans(const float* __restrict__ in,
                                              unsigned short* __restrict__ out,
                                              int R, int C) {
  __shared__ unsigned short t[32][33];
  int tx = threadIdx.x & 31, ty = threadIdx.x >> 5;  // 32 x 8
  int c0 = blockIdx.x * 32, r0 = blockIdx.y * 32;
#pragma unroll
  for (int i = 0; i < 32; i += 8)
    t[ty + i][tx] = f2b(in[(size_t)(r0 + ty + i) * C + c0 + tx]);
  __syncthreads();
#pragma unroll
  for (int i = 0; i < 32; i += 8)
    out[(size_t)(c0 + ty + i) * R + r0 + tx] = t[tx][ty + i];
}

// ---------------- plain cast f32 -> bf16 (vector x4) ------------------------
__global__ __launch_bounds__(256) void castbf(const float* __restrict__ in,
                                              unsigned short* __restrict__ out,
                                              int n4) {
  int i = blockIdx.x * 256 + threadIdx.x;
  if (i >= n4) return;
  float4 v = ((const float4*)in)[i];
  unsigned long long p = (unsigned long long)f2b(v.x) |
                         ((unsigned long long)f2b(v.y) << 16) |
                         ((unsigned long long)f2b(v.z) << 32) |
                         ((unsigned long long)f2b(v.w) << 48);
  ((unsigned long long*)out)[i] = p;
}

// ---------------- LayerNorm rows of 512: f32 in -> bf16 out -----------------
__global__ __launch_bounds__(256) void ln_rows(const float* __restrict__ x,
                                               const float* __restrict__ g,
                                               const float* __restrict__ bb,
                                               unsigned short* __restrict__ out) {
  int row = blockIdx.x * 4 + (threadIdx.x >> 6);
  int lane = threadIdx.x & 63;
  const float* xr = x + (size_t)row * 512 + lane * 8;
  float4 a = *(const float4*)xr;
  float4 c = *(const float4*)(xr + 4);
  float av[8] = {a.x, a.y, a.z, a.w, c.x, c.y, c.z, c.w};
  float s = 0.f, q = 0.f;
#pragma unroll
  for (int j = 0; j < 8; j++) { s += av[j]; q += av[j] * av[j]; }
#pragma unroll
  for (int d = 1; d < 64; d <<= 1) { s += __shfl_xor(s, d); q += __shfl_xor(q, d); }
  float mean = s * (1.f / 512.f);
  float var = q * (1.f / 512.f) - mean * mean;
  float rs = rsqrtf(var + 1e-5f);
  const float* gp = g + lane * 8;
  const float* bp = bb + lane * 8;
  unsigned rr[4];
#pragma unroll
  for (int j = 0; j < 4; j++) {
    float y0 = (av[2 * j] - mean) * rs * gp[2 * j] + bp[2 * j];
    float y1 = (av[2 * j + 1] - mean) * rs * gp[2 * j + 1] + bp[2 * j + 1];
    rr[j] = (unsigned)f2b(y0) | ((unsigned)f2b(y1) << 16);
  }
  *(uint4*)(out + (size_t)row * 512 + lane * 8) = make_uint4(rr[0], rr[1], rr[2], rr[3]);
}

// ---------------- GEMM: C[M,N] = A[M,K] @ Bt[N,K]^T, bf16 in, f32 acc -------
// Staging via global_load_lds 16B/lane (linear LDS rows of 64B, lane order).
// EPI 0: bf16 out;  1: bf16 out + bias;  2: f32 out = acc + bias + res
// EPI 3: f32 out = lengthmask(acc + bias + res); lens points at this
//        kernel's 2-batch window (4096 rows = 2 x 2048).
template <int EPI>
__global__ __launch_bounds__(256) void gemm128(const unsigned short* __restrict__ A,
                                               const unsigned short* __restrict__ Bt,
                                               void* __restrict__ Cp,
                                               const float* __restrict__ bias,
                                               const float* __restrict__ res,
                                               const int* __restrict__ lens,
                                               int M, int N, int K) {
  __shared__ unsigned short As[128 * 32];
  __shared__ unsigned short Bs[128 * 32];
  int tid = threadIdx.x;
  int wave = tid >> 6, lane = tid & 63;
  int row0 = blockIdx.x * 128, col0 = blockIdx.y * 128;
  int wr = wave >> 1, wc = wave & 1;
  f32x4 acc[4][4] = {};
  // staging: wave w covers 32 tile-rows [w*32, w*32+32) in 2 issues per tile
  int srow = wave * 32 + (lane >> 2);
  int scol = (lane & 3) * 8;
  const unsigned short* gA0 = A + (size_t)(row0 + srow) * K + scol;
  const unsigned short* gB0 = Bt + (size_t)(col0 + srow) * K + scol;
  unsigned short* lA0 = &As[(wave * 32) * 32];
  unsigned short* lA1 = &As[(wave * 32 + 16) * 32];
  unsigned short* lB0 = &Bs[(wave * 32) * 32];
  unsigned short* lB1 = &Bs[(wave * 32 + 16) * 32];
  int l15 = lane & 15, l4 = (lane >> 4) << 3;
  int rA = (wr * 64 + l15) * 32 + l4;
  int rB = (wc * 64 + l15) * 32 + l4;
  for (int kt = 0; kt < K; kt += 32) {
    gload16(gA0 + kt, lA0);
    gload16(gA0 + (size_t)16 * K + kt, lA1);
    gload16(gB0 + kt, lB0);
    gload16(gB0 + (size_t)16 * K + kt, lB1);
    __syncthreads();
    bf16x8 af[4], bq[4];
#pragma unroll
    for (int m = 0; m < 4; m++) af[m] = *(const bf16x8*)&As[rA + m * 16 * 32];
#pragma unroll
    for (int n = 0; n < 4; n++) bq[n] = *(const bf16x8*)&Bs[rB + n * 16 * 32];
#pragma unroll
    for (int m = 0; m < 4; m++)
#pragma unroll
      for (int n = 0; n < 4; n++)
        acc[m][n] = mfma16(af[m], bq[n], acc[m][n]);
    __syncthreads();
  }
  int lr = (lane >> 4) * 4;
#pragma unroll
  for (int m = 0; m < 4; m++)
#pragma unroll
    for (int n = 0; n < 4; n++)
#pragma unroll
      for (int r = 0; r < 4; r++) {
        int grow = row0 + wr * 64 + m * 16 + lr + r;
        int gcol = col0 + wc * 64 + n * 16 + l15;
        size_t gi = (size_t)grow * N + gcol;
        float v = acc[m][n][r];
        if (EPI == 0) {
          ((unsigned short*)Cp)[gi] = f2b(v);
        } else if (EPI == 1) {
          ((unsigned short*)Cp)[gi] = f2b(v + bias[gcol]);
        } else if (EPI == 2) {
          ((float*)Cp)[gi] = v + bias[gcol] + res[gi];
        } else {
          int bb = grow >> 11, nn = grow & 2047;
          ((float*)Cp)[gi] = (nn < lens[bb]) ? (v + bias[gcol] + res[gi]) : 0.f;
        }
      }
}

// ---------------- flash attention -------------------------------------------
// grid (nq/64, H=8, B=8); 4 waves x 16 q-rows; KV tiles of 32 keys.
__global__ __launch_bounds__(256) void attn(const unsigned short* __restrict__ Q,
                                            const unsigned short* __restrict__ Kg,
                                            const unsigned short* __restrict__ Vg,
                                            unsigned short* __restrict__ O,
                                            const int* __restrict__ lengths,
                                            int nq, int nkv, int maskkv) {
  int qblk = blockIdx.x, h = blockIdx.y, b = blockIdx.z;
  int tid = threadIdx.x, wave = tid >> 6, lane = tid & 63;
  int len = lengths[b];
  int qbase = qblk * 64;
  if (qbase >= len) return;  // padded q-rows: outputs never read (masked later)
  int kvlen = maskkv ? len : nkv;
  int nt = (kvlen + 31) >> 5;

  __shared__ unsigned short Ks[32][72];   // [key][dh], +8 pad
  __shared__ unsigned short Vf[2048];     // [kgrp 4][dh 64][kj 8] frag-ready
  __shared__ unsigned short Ps[4][16][40];// per-wave P tile [q 16][key 32]+pad

  int l15 = lane & 15, lh = lane >> 4, l4 = lh * 8;
  const unsigned short* qp =
      Q + (size_t)(b * nq + qbase + wave * 16 + l15) * 512 + h * 64 + l4;
  bf16x8 aq0 = *(const bf16x8*)qp;
  bf16x8 aq1 = *(const bf16x8*)(qp + 32);
  const unsigned short* kgp = Kg + (size_t)b * nkv * 512 + h * 64;
  const unsigned short* vgp = Vg + (size_t)b * nkv * 512 + h * 64;

  f32x4 oacc[4] = {};
  float m_r[4], l_r[4];
#pragma unroll
  for (int r = 0; r < 4; r++) { m_r[r] = -3e38f; l_r[r] = 0.f; }

  int skey = tid >> 3, sd0 = (tid & 7) * 8;  // K staging
  int vdh = tid & 63, vkg = tid >> 6;        // V staging

  for (int t = 0; t < nt; t++) {
    int kv0 = t * 32;
    *(uint4*)&Ks[skey][sd0] =
        *(const uint4*)(kgp + (size_t)(kv0 + skey) * 512 + sd0);
    {
      unsigned short tmp[8];
#pragma unroll
      for (int kj = 0; kj < 8; kj++)
        tmp[kj] = vgp[(size_t)(kv0 + vkg * 8 + kj) * 512 + vdh];
      unsigned w0 = (unsigned)tmp[0] | ((unsigned)tmp[1] << 16);
      unsigned w1 = (unsigned)tmp[2] | ((unsigned)tmp[3] << 16);
      unsigned w2 = (unsigned)tmp[4] | ((unsigned)tmp[5] << 16);
      unsigned w3 = (unsigned)tmp[6] | ((unsigned)tmp[7] << 16);
      *(uint4*)&Vf[(vkg * 64 + vdh) * 8] = make_uint4(w0, w1, w2, w3);
    }
    __syncthreads();

    // S = Q K^T * scale (two 16x16 col-fragments)
    f32x4 sf[2];
#pragma unroll
    for (int c = 0; c < 2; c++) {
      bf16x8 bk0 = *(const bf16x8*)&Ks[c * 16 + l15][l4];
      bf16x8 bk1 = *(const bf16x8*)&Ks[c * 16 + l15][32 + l4];
      f32x4 z = {};
      z = mfma16(aq0, bk0, z);
      z = mfma16(aq1, bk1, z);
      sf[c] = z;
    }
#pragma unroll
    for (int c = 0; c < 2; c++) {
      bool kval = (kv0 + c * 16 + l15) < kvlen;
#pragma unroll
      for (int r = 0; r < 4; r++)
        sf[c][r] = kval ? sf[c][r] * 0.125f : -1e30f;
    }
    // online softmax (rows live across 16 lanes: xor 1,2,4,8)
    float mt[4], ps[4];
#pragma unroll
    for (int r = 0; r < 4; r++) mt[r] = fmaxf(sf[0][r], sf[1][r]);
#pragma unroll
    for (int d = 1; d < 16; d <<= 1)
#pragma unroll
      for (int r = 0; r < 4; r++) mt[r] = fmaxf(mt[r], __shfl_xor(mt[r], d));
    float sc[4];
#pragma unroll
    for (int r = 0; r < 4; r++) {
      float mn = fmaxf(m_r[r], mt[r]);
      sc[r] = __expf(m_r[r] - mn);
      m_r[r] = mn;
      ps[r] = 0.f;
    }
#pragma unroll
    for (int c = 0; c < 2; c++)
#pragma unroll
      for (int r = 0; r < 4; r++) {
        float pe = __expf(sf[c][r] - m_r[r]);
        ps[r] += pe;
        Ps[wave][lh * 4 + r][c * 16 + l15] = f2b(pe);
      }
#pragma unroll
    for (int d = 1; d < 16; d <<= 1)
#pragma unroll
      for (int r = 0; r < 4; r++) ps[r] += __shfl_xor(ps[r], d);
#pragma unroll
    for (int r = 0; r < 4; r++) l_r[r] = l_r[r] * sc[r] + ps[r];
#pragma unroll
    for (int nf = 0; nf < 4; nf++)
#pragma unroll
      for (int r = 0; r < 4; r++) oacc[nf][r] *= sc[r];
    // O += P V
    bf16x8 pf = *(const bf16x8*)&Ps[wave][l15][l4];
#pragma unroll
    for (int nf = 0; nf < 4; nf++) {
      bf16x8 vf = *(const bf16x8*)&Vf[(lh * 64 + nf * 16 + l15) * 8];
      oacc[nf] = mfma16(pf, vf, oacc[nf]);
    }
    __syncthreads();
  }
#pragma unroll
  for (int nf = 0; nf < 4; nf++)
#pragma unroll
    for (int r = 0; r < 4; r++) {
      float ov = oacc[nf][r] / l_r[r];
      int qrow = qbase + wave * 16 + lh * 4 + r;
      O[(size_t)(b * nq + qrow) * 512 + h * 64 + nf * 16 + l15] = f2b(ov);
    }
}

// ---------------- GEGLU: p[rows,4096] -> out[rows,2048] ---------------------
__global__ __launch_bounds__(256) void geglu(const unsigned short* __restrict__ p,
                                             unsigned short* __restrict__ out) {
  int idx = blockIdx.x * 256 + threadIdx.x;
  int row = idx >> 8, c = (idx & 255) << 3;
  const unsigned short* pr = p + (size_t)row * 4096 + c;
  uint4 av = *(const uint4*)pr;
  uint4 gv = *(const uint4*)(pr + 2048);
  const unsigned short* ap = (const unsigned short*)&av;
  const unsigned short* gp = (const unsigned short*)&gv;
  unsigned rr[4];
#pragma unroll
  for (int j = 0; j < 4; j++) {
    float a0 = b2f(ap[2 * j]), a1 = b2f(ap[2 * j + 1]);
    float x0 = b2f(gp[2 * j]), x1 = b2f(gp[2 * j + 1]);
    float y0 = a0 * 0.5f * x0 * (1.f + erff(x0 * 0.70710678118f));
    float y1 = a1 * 0.5f * x1 * (1.f + erff(x1 * 0.70710678118f));
    rr[j] = (unsigned)f2b(y0) | ((unsigned)f2b(y1) << 16);
  }
  *(uint4*)(out + (size_t)row * 2048 + c) = make_uint4(rr[0], rr[1], rr[2], rr[3]);
}

// ---------------------------------------------------------------------------
extern "C" void kernel_launch(void* const* d_in, const int* in_sizes, int n_in,
                              void* d_out, int out_size, void* d_ws, size_t ws_size,
                              hipStream_t stream) {
  const float* x = (const float*)d_in[0];
  const float* ctx = (const float*)d_in[1];
  const int* lengths = (const int*)d_in[2];
  const float* wq1 = (const float*)d_in[3];
  const float* wk1 = (const float*)d_in[4];
  const float* wv1 = (const float*)d_in[5];
  const float* wo1 = (const float*)d_in[6];
  const float* bo1 = (const float*)d_in[7];
  const float* wq2 = (const float*)d_in[8];
  const float* wk2 = (const float*)d_in[9];
  const float* wv2 = (const float*)d_in[10];
  const float* wo2 = (const float*)d_in[11];
  const float* bo2 = (const float*)d_in[12];
  const float* wffin = (const float*)d_in[13];
  const float* bffin = (const float*)d_in[14];
  const float* wffout = (const float*)d_in[15];
  const float* bffout = (const float*)d_in[16];
  const float* g1 = (const float*)d_in[17];
  const float* b1 = (const float*)d_in[18];
  const float* g2 = (const float*)d_in[19];
  const float* b2 = (const float*)d_in[20];
  const float* g3 = (const float*)d_in[21];
  const float* b3 = (const float*)d_in[22];

  char* ws = (char*)d_ws;
  size_t o = 0;
  auto alloc = [&](size_t bytes) {
    size_t r = o;
    o += (bytes + 255) & ~(size_t)255;
    return r;
  };
  unsigned short* WQ1T = (unsigned short*)(ws + alloc(512 * 512 * 2));
  unsigned short* WK1T = (unsigned short*)(ws + alloc(512 * 512 * 2));
  unsigned short* WV1T = (unsigned short*)(ws + alloc(512 * 512 * 2));
  unsigned short* WO1T = (unsigned short*)(ws + alloc(512 * 512 * 2));
  unsigned short* WQ2T = (unsigned short*)(ws + alloc(512 * 512 * 2));
  unsigned short* WK2T = (unsigned short*)(ws + alloc(512 * 768 * 2));
  unsigned short* WV2T = (unsigned short*)(ws + alloc(512 * 768 * 2));
  unsigned short* WO2T = (unsigned short*)(ws + alloc(512 * 512 * 2));
  unsigned short* WFFINT = (unsigned short*)(ws + alloc(4096 * 512 * 2));
  unsigned short* WFFOUTT = (unsigned short*)(ws + alloc(512 * 2048 * 2));
  float* XBUF = (float*)(ws + alloc((size_t)16384 * 512 * 4));
  unsigned short* HB = (unsigned short*)(ws + alloc((size_t)16384 * 512 * 2));
  unsigned short* QB = (unsigned short*)(ws + alloc((size_t)16384 * 512 * 2));
  unsigned short* KB = (unsigned short*)(ws + alloc((size_t)16384 * 512 * 2));
  unsigned short* VB = (unsigned short*)(ws + alloc((size_t)16384 * 512 * 2));
  unsigned short* AO = (unsigned short*)(ws + alloc((size_t)16384 * 512 * 2));
  // phase-local aliases
  unsigned short* CTXB = KB;                                   // 3 MB (attn2 only)
  unsigned short* K2B = KB + (size_t)4 * 1024 * 1024 / 2;      // 2 MB at +4MB
  unsigned short* V2B = KB + (size_t)8 * 1024 * 1024 / 2;      // 2 MB at +8MB
  unsigned short* PCH = QB;   // spans QB..KB (32 MB contiguous) during FF
  unsigned short* GCH = VB;   // 16 MB during FF

  // weight prep
  wtrans<<<dim3(16, 16), 256, 0, stream>>>(wq1, WQ1T, 512, 512);
  wtrans<<<dim3(16, 16), 256, 0, stream>>>(wk1, WK1T, 512, 512);
  wtrans<<<dim3(16, 16), 256, 0, stream>>>(wv1, WV1T, 512, 512);
  wtrans<<<dim3(16, 16), 256, 0, stream>>>(wo1, WO1T, 512, 512);
  wtrans<<<dim3(16, 16), 256, 0, stream>>>(wq2, WQ2T, 512, 512);
  wtrans<<<dim3(16, 24), 256, 0, stream>>>(wk2, WK2T, 768, 512);
  wtrans<<<dim3(16, 24), 256, 0, stream>>>(wv2, WV2T, 768, 512);
  wtrans<<<dim3(16, 16), 256, 0, stream>>>(wo2, WO2T, 512, 512);
  wtrans<<<dim3(128, 16), 256, 0, stream>>>(wffin, WFFINT, 512, 4096);
  wtrans<<<dim3(16, 64), 256, 0, stream>>>(wffout, WFFOUTT, 2048, 512);

  // --- attn1 (self, key-masked) ---
  ln_rows<<<4096, 256, 0, stream>>>(x, g1, b1, HB);
  gemm128<0><<<dim3(128, 4), 256, 0, stream>>>(HB, WQ1T, QB, nullptr, nullptr, nullptr, 16384, 512, 512);
  gemm128<0><<<dim3(128, 4), 256, 0, stream>>>(HB, WK1T, KB, nullptr, nullptr, nullptr, 16384, 512, 512);
  gemm128<0><<<dim3(128, 4), 256, 0, stream>>>(HB, WV1T, VB, nullptr, nullptr, nullptr, 16384, 512, 512);
  attn<<<dim3(32, 8, 8), 256, 0, stream>>>(QB, KB, VB, AO, lengths, 2048, 2048, 1);
  gemm128<2><<<dim3(128, 4), 256, 0, stream>>>(AO, WO1T, XBUF, bo1, x, nullptr, 16384, 512, 512);

  // --- attn2 (cross, dense context) ---
  // castbf runs HERE: CTXB aliases KB, which attn1's K-projection used.
  ln_rows<<<4096, 256, 0, stream>>>(XBUF, g2, b2, HB);
  castbf<<<1536, 256, 0, stream>>>(ctx, CTXB, 2048 * 768 / 4);
  gemm128<0><<<dim3(128, 4), 256, 0, stream>>>(HB, WQ2T, QB, nullptr, nullptr, nullptr, 16384, 512, 512);
  gemm128<0><<<dim3(16, 4), 256, 0, stream>>>(CTXB, WK2T, K2B, nullptr, nullptr, nullptr, 2048, 512, 768);
  gemm128<0><<<dim3(16, 4), 256, 0, stream>>>(CTXB, WV2T, V2B, nullptr, nullptr, nullptr, 2048, 512, 768);
  attn<<<dim3(32, 8, 8), 256, 0, stream>>>(QB, K2B, V2B, AO, lengths, 2048, 256, 0);
  gemm128<2><<<dim3(128, 4), 256, 0, stream>>>(AO, WO2T, XBUF, bo2, XBUF, nullptr, 16384, 512, 512);

  // --- GEGLU FF, 4 row-chunks of 4096; FF-out fuses mask -> d_out ---
  ln_rows<<<4096, 256, 0, stream>>>(XBUF, g3, b3, HB);
  for (int ch = 0; ch < 4; ch++) {
    const unsigned short* hc = HB + (size_t)ch * 4096 * 512;
    float* xc = XBUF + (size_t)ch * 4096 * 512;
    float* oc = (float*)d_out + (size_t)ch * 4096 * 512;
    gemm128<1><<<dim3(32, 32), 256, 0, stream>>>(hc, WFFINT, PCH, bffin, nullptr, nullptr, 4096, 4096, 512);
    geglu<<<4096, 256, 0, stream>>>(PCH, GCH);
    gemm128<3><<<dim3(32, 4), 256, 0, stream>>>(GCH, WFFOUTT, oc, bffout, xc, lengths + ch * 2, 4096, 512, 2048);
  }
}